// Round 1
// baseline (1953.343 us; speedup 1.0000x reference)
//
#include <hip/hip_runtime.h>
#include <cstdint>

#define DEV __device__ __forceinline__

typedef _Float16 f16;
typedef _Float16 f16x8 __attribute__((ext_vector_type(8)));
typedef float f32x4 __attribute__((ext_vector_type(4)));
typedef unsigned int u32;

DEV void gll16(const void* g, void* l) {
  __builtin_amdgcn_global_load_lds((const __attribute__((address_space(1))) u32*)g,
                                   (__attribute__((address_space(3))) u32*)l, 16, 0, 0);
}

DEV float block_sum(float v, float* red) {
#pragma unroll
  for (int o = 32; o; o >>= 1) v += __shfl_xor(v, o);
  int w = threadIdx.x >> 6;
  __syncthreads();
  if ((threadIdx.x & 63) == 0) red[w] = v;
  __syncthreads();
  return red[0] + red[1] + red[2] + red[3];
}

// ---------------- weight transpose+cvt: W[K][N] f32 -> BT[Npad][Kpad] f16 ----------------
__global__ void k_trans(const float* __restrict__ W, f16* __restrict__ BT, int K, int N, int Kpad) {
  __shared__ float t[32][33];
  int n0 = blockIdx.x * 32, k0 = blockIdx.y * 32, tx = threadIdx.x, ty = threadIdx.y;
  for (int i = ty; i < 32; i += 8) {
    int k = k0 + i, n = n0 + tx;
    t[i][tx] = (k < K && n < N) ? W[(size_t)k * N + n] : 0.f;
  }
  __syncthreads();
  for (int i = ty; i < 32; i += 8)
    BT[(size_t)(n0 + i) * Kpad + k0 + tx] = (f16)t[tx][i];
}

__global__ void k_trans3(const float* __restrict__ Wq, const float* __restrict__ Wk,
                         const float* __restrict__ Wv, f16* __restrict__ BT) {
  __shared__ float t[32][33];
  const float* W = (blockIdx.z == 0) ? Wq : (blockIdx.z == 1) ? Wk : Wv;
  f16* dst = BT + (size_t)blockIdx.z * 512 * 512;
  int n0 = blockIdx.x * 32, k0 = blockIdx.y * 32, tx = threadIdx.x, ty = threadIdx.y;
  for (int i = ty; i < 32; i += 8) t[i][tx] = W[(size_t)(k0 + i) * 512 + n0 + tx];
  __syncthreads();
  for (int i = ty; i < 32; i += 8) dst[(size_t)(n0 + i) * 512 + k0 + tx] = (f16)t[tx][i];
}

// ---------------- GEMM: C[M][Nstride] f32 = A[M][K]f16 * BT[N][K]f16^T ----------------
template <int BM, int BN>
__launch_bounds__(256)
__global__ void k_gemm(const f16* __restrict__ A, const f16* __restrict__ BT,
                       float* __restrict__ C, int K, int Nstride) {
  constexpr int BK = 32;
  constexpr int FM = BM / 32, FN = BN / 32;
  __shared__ f16 sA[BM * BK];
  __shared__ f16 sB[BN * BK];
  const int tid = threadIdx.x, wid = tid >> 6, lane = tid & 63;
  const int m0 = blockIdx.x * BM, n0 = blockIdx.y * BN;
  const int wm = wid >> 1, wn = wid & 1;
  f32x4 acc[FM][FN];
#pragma unroll
  for (int i = 0; i < FM; i++)
#pragma unroll
    for (int j = 0; j < FN; j++) acc[i][j] = (f32x4){0.f, 0.f, 0.f, 0.f};
  const char* Ab = (const char*)A + (size_t)m0 * K * 2;
  const char* Bb = (const char*)BT + (size_t)n0 * K * 2;
  const size_t rowB = (size_t)K * 2;
  for (int k0 = 0; k0 < K; k0 += BK) {
    for (int i = wid; i < BM / 16; i += 4)
      gll16(Ab + (size_t)(i * 16 + (lane >> 2)) * rowB + k0 * 2 + (lane & 3) * 16,
            (char*)sA + i * 1024);
    for (int i = wid; i < BN / 16; i += 4)
      gll16(Bb + (size_t)(i * 16 + (lane >> 2)) * rowB + k0 * 2 + (lane & 3) * 16,
            (char*)sB + i * 1024);
    __syncthreads();
    f16x8 af[FM], bfr[FN];
#pragma unroll
    for (int i = 0; i < FM; i++)
      af[i] = *(const f16x8*)(sA + (wm * (BM / 2) + i * 16 + (lane & 15)) * BK + (lane >> 4) * 8);
#pragma unroll
    for (int j = 0; j < FN; j++)
      bfr[j] = *(const f16x8*)(sB + (wn * (BN / 2) + j * 16 + (lane & 15)) * BK + (lane >> 4) * 8);
#pragma unroll
    for (int i = 0; i < FM; i++)
#pragma unroll
      for (int j = 0; j < FN; j++)
        acc[i][j] = __builtin_amdgcn_mfma_f32_16x16x32_f16(af[i], bfr[j], acc[i][j], 0, 0, 0);
    __syncthreads();
  }
#pragma unroll
  for (int i = 0; i < FM; i++) {
    int row0 = m0 + wm * (BM / 2) + i * 16 + ((lane >> 4) * 4);
#pragma unroll
    for (int j = 0; j < FN; j++) {
      int col = n0 + wn * (BN / 2) + j * 16 + (lane & 15);
#pragma unroll
      for (int r = 0; r < 4; r++) C[(size_t)(row0 + r) * Nstride + col] = acc[i][j][r];
    }
  }
}

// ---------------- embed + add_time + LN1 ----------------
__global__ void k_embed(const int* __restrict__ tok, const float* __restrict__ tbl,
                        const float* __restrict__ g, const float* __restrict__ bsh,
                        float* __restrict__ x, f16* __restrict__ act) {
  __shared__ float red[4];
  const int m = blockIdx.x, tid = threadIdx.x;
  const float* e = tbl + (size_t)tok[m] * 511;
  float e0 = (tid < 511) ? e[tid] : 0.f;
  float e1 = (tid + 256 < 511) ? e[tid + 256] : 0.f;
  float s1 = block_sum(e0 + e1, red);
  float s2 = block_sum(e0 * e0 + e1 * e1, red);
  float t = sqrtf(s2 + 1.f);
  float* xr = x + (size_t)m * 512;
  if (tid == 0) xr[0] = t;
  if (tid < 511) xr[1 + tid] = e0;
  if (tid + 256 < 511) xr[257 + tid] = e1;
  float mu = s1 / 511.f;
  float var = s2 / 511.f - mu * mu;
  float inv = rsqrtf(var + 1e-5f);
  float n0 = (tid < 511) ? (e0 - mu) * inv * g[tid] + bsh[tid] : 0.f;
  float n1 = (tid + 256 < 511) ? (e1 - mu) * inv * g[tid + 256] + bsh[tid + 256] : 0.f;
  float sn = block_sum(n0 * n0 + n1 * n1, red);
  float t2 = sqrtf(sn + 1.f);
  f16* ar = act + (size_t)m * 512;
  if (tid == 0) ar[0] = (f16)t2;
  if (tid < 511) ar[1 + tid] = (f16)n0;
  if (tid + 256 < 511) ar[257 + tid] = (f16)n1;
}

// ---------------- qkv bias + per-head add_time -> q(scaled)/k/vT fp16 ----------------
__launch_bounds__(64)
__global__ void k_qkvsplit(const float* __restrict__ raw, const float* __restrict__ bq,
                           const float* __restrict__ bk, const float* __restrict__ bv,
                           f16* __restrict__ qhat, f16* __restrict__ khat, f16* __restrict__ vT) {
  const int m = blockIdx.x, grp = blockIdx.y, typ = grp >> 3, h = grp & 7, lane = threadIdx.x;
  const float* bb = (typ == 0) ? bq : (typ == 1) ? bk : bv;
  float v = raw[(size_t)m * 1536 + typ * 512 + h * 64 + lane] + bb[h * 64 + lane];
  float s2 = v * v;
#pragma unroll
  for (int o = 32; o; o >>= 1) s2 += __shfl_xor(s2, o);
  float t = sqrtf(s2 + 1.0f);
  const int b = m >> 10, s = m & 1023, bh = b * 8 + h;
  if (typ == 0) {
    size_t base = ((size_t)bh * 1024 + s) * 88;
    qhat[base + lane] = (f16)(0.25f * v);
    if (lane == 0) qhat[base + 64] = (f16)(0.25f * t);
  } else if (typ == 1) {
    size_t base = ((size_t)bh * 1024 + s) * 88;
    khat[base + lane] = (f16)v;
    if (lane == 0) khat[base + 64] = (f16)t;
  } else {
    vT[((size_t)bh * 80 + lane) * 1024 + s] = (f16)v;
    if (lane == 0) vT[((size_t)bh * 80 + 64) * 1024 + s] = (f16)t;
  }
}

// ---------------- flash attention + l_project ----------------
__launch_bounds__(256)
__global__ void k_attn(const f16* __restrict__ qhat, const f16* __restrict__ khat,
                       const f16* __restrict__ vT, f16* __restrict__ ao) {
  __shared__ f16 sK[64 * 88];
  __shared__ f16 sV[80 * 72];
  __shared__ f16 sP[4][16 * 80];
  const int bh = blockIdx.x, qt = blockIdx.y, q0 = qt * 64;
  const int tid = threadIdx.x, wid = tid >> 6, lane = tid & 63;
  const int l15 = lane & 15, l4 = lane >> 4;
  const f16* qpl = qhat + (size_t)bh * 1024 * 88;
  const f16* kpl = khat + (size_t)bh * 1024 * 88;
  const f16* vpl = vT + (size_t)bh * 80 * 1024;
  const int qrow = q0 + wid * 16;
  f16x8 qf0 = *(const f16x8*)(qpl + (size_t)(qrow + l15) * 88 + l4 * 8);
  f16x8 qf1 = *(const f16x8*)(qpl + (size_t)(qrow + l15) * 88 + 32 + l4 * 8);
  float qth[4];
#pragma unroll
  for (int r = 0; r < 4; r++) qth[r] = (float)qpl[(size_t)(qrow + l4 * 4 + r) * 88 + 64];
  f32x4 acc[5];
#pragma unroll
  for (int i = 0; i < 5; i++) acc[i] = (f32x4){0, 0, 0, 0};
  float mrun[4] = {-3e38f, -3e38f, -3e38f, -3e38f}, lrun[4] = {0, 0, 0, 0};
  const int ntiles = qt + 1;
  for (int jt = 0; jt < ntiles; ++jt) {
    int j0 = jt * 64;
    for (int i = wid; i < 11; i += 4)
      gll16((const char*)kpl + (size_t)j0 * 176 + i * 1024 + lane * 16, (char*)sK + i * 1024);
    for (int idx = tid; idx < 640; idx += 256) {
      int row = idx >> 3, c = idx & 7;
      *(int4*)(sV + row * 72 + c * 8) = *(const int4*)(vpl + (size_t)row * 1024 + j0 + c * 8);
    }
    __syncthreads();
    f32x4 sc[4];
#pragma unroll
    for (int fn = 0; fn < 4; fn++) {
      const f16* kb = sK + (fn * 16 + l15) * 88;
      f16x8 k0v = *(const f16x8*)(kb + l4 * 8);
      f16x8 k1v = *(const f16x8*)(kb + 32 + l4 * 8);
      f32x4 a = (f32x4){0, 0, 0, 0};
      a = __builtin_amdgcn_mfma_f32_16x16x32_f16(qf0, k0v, a, 0, 0, 0);
      a = __builtin_amdgcn_mfma_f32_16x16x32_f16(qf1, k1v, a, 0, 0, 0);
      sc[fn] = a;
    }
    float s[4][4];
#pragma unroll
    for (int fn = 0; fn < 4; fn++) {
      float ktc = (float)sK[(fn * 16 + l15) * 88 + 64];
      int col = j0 + fn * 16 + l15;
#pragma unroll
      for (int r = 0; r < 4; r++) {
        int row = q0 + wid * 16 + l4 * 4 + r;
        float v = sc[fn][r] - qth[r] * ktc;
        s[fn][r] = (col <= row) ? v : -3e38f;
      }
    }
    float mnew[4], al[4], rs[4];
#pragma unroll
    for (int r = 0; r < 4; r++) {
      float t = fmaxf(fmaxf(s[0][r], s[1][r]), fmaxf(s[2][r], s[3][r]));
#pragma unroll
      for (int o = 8; o; o >>= 1) t = fmaxf(t, __shfl_xor(t, o));
      mnew[r] = fmaxf(mrun[r], t);
      al[r] = exp2f((mrun[r] - mnew[r]) * 1.44269504f);
      mrun[r] = mnew[r];
      rs[r] = 0.f;
    }
    f16* sPw = sP[wid];
#pragma unroll
    for (int fn = 0; fn < 4; fn++)
#pragma unroll
      for (int r = 0; r < 4; r++) {
        float p = exp2f((s[fn][r] - mnew[r]) * 1.44269504f);
        rs[r] += p;
        sPw[(l4 * 4 + r) * 80 + fn * 16 + l15] = (f16)p;
      }
#pragma unroll
    for (int r = 0; r < 4; r++) {
#pragma unroll
      for (int o = 8; o; o >>= 1) rs[r] += __shfl_xor(rs[r], o);
      lrun[r] = lrun[r] * al[r] + rs[r];
    }
#pragma unroll
    for (int fd = 0; fd < 5; fd++)
#pragma unroll
      for (int r = 0; r < 4; r++) acc[fd][r] *= al[r];
#pragma unroll
    for (int ks = 0; ks < 2; ks++) {
      f16x8 pf = *(const f16x8*)(sPw + l15 * 80 + ks * 32 + l4 * 8);
#pragma unroll
      for (int fd = 0; fd < 5; fd++) {
        f16x8 vf = *(const f16x8*)(sV + (fd * 16 + l15) * 72 + ks * 32 + l4 * 8);
        acc[fd] = __builtin_amdgcn_mfma_f32_16x16x32_f16(pf, vf, acc[fd], 0, 0, 0);
      }
    }
    __syncthreads();
  }
  const int b = bh >> 3, h = bh & 7;
#pragma unroll
  for (int r = 0; r < 4; r++) {
    float invl = 1.0f / lrun[r];
    float ss = 0.f;
    float ov[4];
#pragma unroll
    for (int fd = 0; fd < 4; fd++) {
      ov[fd] = acc[fd][r] * invl;
      ss += ov[fd] * ov[fd];
    }
#pragma unroll
    for (int o = 8; o; o >>= 1) ss += __shfl_xor(ss, o);
    float tv = acc[4][r] * invl;
    tv = __shfl(tv, lane & 48);
    float scp = rsqrtf(fmaxf(tv * tv - ss, 1e-6f));
    int row = q0 + wid * 16 + l4 * 4 + r;
    size_t rb = ((size_t)b * 1024 + row) * 544 + h * 65;
    if (l15 == 0) ao[rb] = (f16)(tv * scp);
#pragma unroll
    for (int fd = 0; fd < 4; fd++) ao[rb + 1 + fd * 16 + l15] = (f16)(ov[fd] * scp);
  }
}

// ---------------- residual + l_project (+ optional LN) ----------------
__global__ void k_resproj(float* __restrict__ x, const float* __restrict__ raw,
                          const float* __restrict__ bias, const float* __restrict__ resw, int li,
                          const float* __restrict__ g, const float* __restrict__ bsh,
                          f16* __restrict__ act, int applyLN) {
  __shared__ float red[4];
  const int m = blockIdx.x, tid = threadIdx.x;
  const float* rr = raw + (size_t)m * 512;
  float* xr = x + (size_t)m * 512;
  const float rw = resw[li];
  float y0 = (tid < 511) ? rr[tid] + bias[tid] : 0.f;
  float y1 = (tid + 256 < 511) ? rr[tid + 256] + bias[tid + 256] : 0.f;
  float s2 = block_sum(y0 * y0 + y1 * y1, red);
  float tax = sqrtf(s2 + 1.f);
  float xt = xr[0];
  float u0 = (tid < 511) ? xr[1 + tid] + rw * y0 : 0.f;
  float u1 = (tid + 256 < 511) ? xr[257 + tid] + rw * y1 : 0.f;
  float ut = xt + rw * tax;
  float su = block_sum(u0 + u1, red);
  float su2 = block_sum(u0 * u0 + u1 * u1, red);
  float scp = rsqrtf(fmaxf(ut * ut - su2, 1e-6f));
  float nx0 = u0 * scp, nx1 = u1 * scp, nxt = ut * scp;
  if (tid == 0) xr[0] = nxt;
  if (tid < 511) xr[1 + tid] = nx0;
  if (tid + 256 < 511) xr[257 + tid] = nx1;
  f16* ar = act + (size_t)m * 512;
  if (applyLN) {
    float mu = su * scp / 511.f;
    float var = su2 * scp * scp / 511.f - mu * mu;
    float inv = rsqrtf(var + 1e-5f);
    float n0 = (tid < 511) ? (nx0 - mu) * inv * g[tid] + bsh[tid] : 0.f;
    float n1 = (tid + 256 < 511) ? (nx1 - mu) * inv * g[tid + 256] + bsh[tid + 256] : 0.f;
    float sn = block_sum(n0 * n0 + n1 * n1, red);
    float t2 = sqrtf(sn + 1.f);
    if (tid == 0) ar[0] = (f16)t2;
    if (tid < 511) ar[1 + tid] = (f16)n0;
    if (tid + 256 < 511) ar[257 + tid] = (f16)n1;
  } else {
    if (tid == 0) ar[0] = (f16)nxt;
    if (tid < 511) ar[1 + tid] = (f16)nx0;
    if (tid + 256 < 511) ar[257 + tid] = (f16)nx1;
  }
}

// ---------------- bias + gelu + add_time (fc activation) ----------------
__global__ void k_gelu(const float* __restrict__ raw, const float* __restrict__ bias,
                       f16* __restrict__ act) {
  __shared__ float red[4];
  const int m = blockIdx.x, tid = threadIdx.x;
  const float* rr = raw + (size_t)m * 2048;
  float gv[8];
  float s2 = 0.f;
#pragma unroll
  for (int i = 0; i < 8; i++) {
    int j = i * 256 + tid;
    float y = (j < 2047) ? rr[j] + bias[j] : 0.f;
    float c = y * y * y;
    float gg = 0.5f * y * (1.f + tanhf(0.7978845608f * (y + 0.044715f * c)));
    if (j >= 2047) gg = 0.f;
    gv[i] = gg;
    s2 += gg * gg;
  }
  s2 = block_sum(s2, red);
  float t = sqrtf(s2 + 1.f);
  f16* ar = act + (size_t)m * 2048;
  if (tid == 0) ar[0] = (f16)t;
#pragma unroll
  for (int i = 0; i < 8; i++) {
    int j = i * 256 + tid;
    if (j < 2047) ar[1 + j] = (f16)gv[i];
  }
}

// ---------------- final bias + LN -> out ----------------
__global__ void k_final(const float* __restrict__ raw, const float* __restrict__ bias,
                        const float* __restrict__ g, const float* __restrict__ bsh,
                        float* __restrict__ out) {
  __shared__ float red[4];
  const int m = blockIdx.x, tid = threadIdx.x;
  const float* rr = raw + (size_t)m * 512;
  float y0 = (tid < 511) ? rr[tid] + bias[tid] : 0.f;
  float y1 = (tid + 256 < 511) ? rr[tid + 256] + bias[tid + 256] : 0.f;
  float s1 = block_sum(y0 + y1, red);
  float s2 = block_sum(y0 * y0 + y1 * y1, red);
  float mu = s1 / 511.f;
  float var = s2 / 511.f - mu * mu;
  float inv = rsqrtf(var + 1e-5f);
  float n0 = (tid < 511) ? (y0 - mu) * inv * g[tid] + bsh[tid] : 0.f;
  float n1 = (tid + 256 < 511) ? (y1 - mu) * inv * g[tid + 256] + bsh[tid + 256] : 0.f;
  float sn = block_sum(n0 * n0 + n1 * n1, red);
  float t2 = sqrtf(sn + 1.f);
  float* orow = out + (size_t)m * 512;
  if (tid == 0) orow[0] = t2;
  if (tid < 511) orow[1 + tid] = n0;
  if (tid + 256 < 511) orow[257 + tid] = n1;
}

extern "C" void kernel_launch(void* const* d_in, const int* in_sizes, int n_in,
                              void* d_out, int out_size, void* d_ws, size_t ws_size,
                              hipStream_t stream) {
  (void)in_sizes; (void)n_in; (void)out_size; (void)ws_size;
  const int* tok = (const int*)d_in[0];
  const float* etab = (const float*)d_in[1];
  const float* Wq = (const float*)d_in[2];
  const float* bq = (const float*)d_in[3];
  const float* Wk = (const float*)d_in[4];
  const float* bk = (const float*)d_in[5];
  const float* Wv = (const float*)d_in[6];
  const float* bv = (const float*)d_in[7];
  const float* Wo = (const float*)d_in[8];
  const float* bo = (const float*)d_in[9];
  const float* ln1g = (const float*)d_in[10];
  const float* ln1b = (const float*)d_in[11];
  const float* ln2g = (const float*)d_in[12];
  const float* ln2b = (const float*)d_in[13];
  const float* Wfc = (const float*)d_in[14];
  const float* bfc = (const float*)d_in[15];
  const float* Wpr = (const float*)d_in[16];
  const float* bpr = (const float*)d_in[17];
  const float* rw1 = (const float*)d_in[18];
  const float* rw2 = (const float*)d_in[19];
  const float* Wfin = (const float*)d_in[20];
  const float* bfin = (const float*)d_in[21];
  const float* lnfg = (const float*)d_in[22];
  const float* lnfb = (const float*)d_in[23];

  char* wsb = (char*)d_ws;
  size_t off = 0;
  auto alloc = [&](size_t bytes) -> char* {
    char* p = wsb + off;
    off = (off + bytes + 1023) & ~(size_t)1023;
    return p;
  };
  float* x = (float*)alloc(2048ull * 512 * 4);
  f16* actA = (f16*)alloc(2048ull * 512 * 2);
  float* raw = (float*)alloc(2048ull * 2048 * 4);
  f16* qhat = (f16*)alloc(16ull * 1024 * 88 * 2);
  f16* khat = (f16*)alloc(16ull * 1024 * 88 * 2);
  f16* vT = (f16*)alloc(16ull * 80 * 1024 * 2);
  f16* ao = (f16*)alloc(2048ull * 544 * 2);
  f16* fcact = (f16*)alloc(2048ull * 2048 * 2);
  f16* wqkvT = (f16*)alloc(1536ull * 512 * 2);
  f16* woT = (f16*)alloc(512ull * 544 * 2);
  f16* wfcT = (f16*)alloc(2048ull * 512 * 2);
  f16* wprT = (f16*)alloc(512ull * 2048 * 2);
  f16* wfinT = (f16*)alloc(512ull * 512 * 2);

  k_embed<<<2048, 256, 0, stream>>>(tok, etab, ln1g, ln1b, x, actA);

  for (int li = 0; li < 12; li++) {
    const float* Wq_l = Wq + (size_t)li * 512 * 512;
    const float* Wk_l = Wk + (size_t)li * 512 * 512;
    const float* Wv_l = Wv + (size_t)li * 512 * 512;
    const float* Wo_l = Wo + (size_t)li * 520 * 511;
    const float* Wfc_l = Wfc + (size_t)li * 512 * 2047;
    const float* Wpr_l = Wpr + (size_t)li * 2048 * 511;
    const float* bq_l = bq + (size_t)li * 512;
    const float* bk_l = bk + (size_t)li * 512;
    const float* bv_l = bv + (size_t)li * 512;
    const float* bo_l = bo + (size_t)li * 511;
    const float* bfc_l = bfc + (size_t)li * 2047;
    const float* bpr_l = bpr + (size_t)li * 511;
    const float* ln2g_l = ln2g + (size_t)li * 511;
    const float* ln2b_l = ln2b + (size_t)li * 511;

    k_trans3<<<dim3(16, 16, 3), dim3(32, 8), 0, stream>>>(Wq_l, Wk_l, Wv_l, wqkvT);
    k_trans<<<dim3(16, 17), dim3(32, 8), 0, stream>>>(Wo_l, woT, 520, 511, 544);
    k_trans<<<dim3(64, 16), dim3(32, 8), 0, stream>>>(Wfc_l, wfcT, 512, 2047, 512);
    k_trans<<<dim3(16, 64), dim3(32, 8), 0, stream>>>(Wpr_l, wprT, 2048, 511, 2048);

    k_gemm<128, 128><<<dim3(16, 12), 256, 0, stream>>>(actA, wqkvT, raw, 512, 1536);
    k_qkvsplit<<<dim3(2048, 24), 64, 0, stream>>>(raw, bq_l, bk_l, bv_l, qhat, khat, vT);
    k_attn<<<dim3(16, 16), 256, 0, stream>>>(qhat, khat, vT, ao);
    k_gemm<64, 64><<<dim3(32, 8), 256, 0, stream>>>(ao, woT, raw, 544, 512);
    k_resproj<<<2048, 256, 0, stream>>>(x, raw, bo_l, rw1, li, ln2g_l, ln2b_l, actA, 1);
    k_gemm<128, 128><<<dim3(16, 16), 256, 0, stream>>>(actA, wfcT, raw, 512, 2048);
    k_gelu<<<2048, 256, 0, stream>>>(raw, bfc_l, fcact);
    k_gemm<64, 64><<<dim3(32, 8), 256, 0, stream>>>(fcact, wprT, raw, 2048, 512);
    const float* ng = (li < 11) ? ln1g + (size_t)(li + 1) * 511 : ln1g;
    const float* nb = (li < 11) ? ln1b + (size_t)(li + 1) * 511 : ln1b;
    k_resproj<<<2048, 256, 0, stream>>>(x, raw, bpr_l, rw2, li, ng, nb, actA, (li < 11) ? 1 : 0);
  }

  k_trans<<<dim3(16, 16), dim3(32, 8), 0, stream>>>(Wfin, wfinT, 512, 511, 512);
  k_gemm<64, 64><<<dim3(32, 8), 256, 0, stream>>>(actA, wfinT, raw, 512, 512);
  k_final<<<2048, 256, 0, stream>>>(raw, bfin, lnfg, lnfb, (float*)d_out);
}

// Round 2
// 1650.165 us; speedup vs baseline: 1.1837x; 1.1837x over previous
//
#include <hip/hip_runtime.h>
#include <cstdint>

#define DEV __device__ __forceinline__

typedef _Float16 f16;
typedef _Float16 f16x8 __attribute__((ext_vector_type(8)));
typedef float f32x4 __attribute__((ext_vector_type(4)));
typedef unsigned int u32;

DEV void gll16(const void* g, void* l) {
  __builtin_amdgcn_global_load_lds((const __attribute__((address_space(1))) u32*)g,
                                   (__attribute__((address_space(3))) u32*)l, 16, 0, 0);
}

DEV float block_sum(float v, float* red) {
#pragma unroll
  for (int o = 32; o; o >>= 1) v += __shfl_xor(v, o);
  int w = threadIdx.x >> 6;
  __syncthreads();
  if ((threadIdx.x & 63) == 0) red[w] = v;
  __syncthreads();
  return red[0] + red[1] + red[2] + red[3];
}

// ---------------- weight transpose+cvt: W[K][N] f32 -> BT[Npad][Kpad] f16, per-layer z ----------------
__global__ void k_trans(const float* __restrict__ W0, f16* __restrict__ BT0, int K, int N, int Kpad,
                        size_t srcStride, size_t dstStride) {
  __shared__ float t[32][33];
  const float* W = W0 + (size_t)blockIdx.z * srcStride;
  f16* BT = BT0 + (size_t)blockIdx.z * dstStride;
  int n0 = blockIdx.x * 32, k0 = blockIdx.y * 32, tx = threadIdx.x, ty = threadIdx.y;
  for (int i = ty; i < 32; i += 8) {
    int k = k0 + i, n = n0 + tx;
    t[i][tx] = (k < K && n < N) ? W[(size_t)k * N + n] : 0.f;
  }
  __syncthreads();
  for (int i = ty; i < 32; i += 8)
    BT[(size_t)(n0 + i) * Kpad + k0 + tx] = (f16)t[tx][i];
}

__global__ void k_trans3(const float* __restrict__ Wq, const float* __restrict__ Wk,
                         const float* __restrict__ Wv, f16* __restrict__ BT) {
  __shared__ float t[32][33];
  const int layer = blockIdx.z / 3, typ = blockIdx.z % 3;
  const float* W = ((typ == 0) ? Wq : (typ == 1) ? Wk : Wv) + (size_t)layer * 262144;
  f16* dst = BT + (size_t)layer * 786432 + (size_t)typ * 262144;
  int n0 = blockIdx.x * 32, k0 = blockIdx.y * 32, tx = threadIdx.x, ty = threadIdx.y;
  for (int i = ty; i < 32; i += 8) t[i][tx] = W[(size_t)(k0 + i) * 512 + n0 + tx];
  __syncthreads();
  for (int i = ty; i < 32; i += 8) dst[(size_t)(n0 + i) * 512 + k0 + tx] = (f16)t[tx][i];
}

// ---------------- GEMM: acc = A[M][lda]f16 * BT[N][ldb]f16^T, BK=64, swizzled LDS ----------------
// EPI 0: O1[row*ldc+col] = acc
// EPI 1: QKV epilogue -> qhat(H1)/khat(H2)/vT(H3), biases c0/c1/c2  (BM=BN=128 only)
// EPI 2: bias(c0)+gelu -> H1 (f16 [M][2048], col2047=0), atomicAdd ssq  (BM=BN=128 only)
// EPI 3: O = (z?O2:O1); z==0 adds rank-1 t(ssq)*c0[col] (col<511)
template <int BM, int BN, int EPI>
__launch_bounds__(256)
__global__ void k_gemm(const f16* __restrict__ A, const f16* __restrict__ BT,
                       int lda, int ldb, int klen,
                       float* __restrict__ O1, float* __restrict__ O2, int ldc,
                       const float* __restrict__ c0, const float* __restrict__ c1,
                       const float* __restrict__ c2, float* __restrict__ ssq,
                       f16* __restrict__ H1, f16* __restrict__ H2, f16* __restrict__ H3) {
  constexpr int FM = BM / 32, FN = BN / 32;
  __shared__ f16 sA[BM * 64];
  __shared__ f16 sB[BN * 64];
  const int tid = threadIdx.x, wid = tid >> 6, lane = tid & 63;
  const int l15 = lane & 15, l4 = lane >> 4;
  const int m0 = blockIdx.x * BM, n0 = blockIdx.y * BN;
  const int wm = wid >> 1, wn = wid & 1;
  const int kbeg = blockIdx.z * klen;
  f32x4 acc[FM][FN];
#pragma unroll
  for (int i = 0; i < FM; i++)
#pragma unroll
    for (int j = 0; j < FN; j++) acc[i][j] = (f32x4){0.f, 0.f, 0.f, 0.f};
  const size_t ldab = (size_t)lda * 2, ldbb = (size_t)ldb * 2;
  const int swz = ((lane & 7) ^ (lane >> 3)) * 16;
  const char* Ab = (const char*)A + (size_t)m0 * ldab + (size_t)(lane >> 3) * ldab + swz;
  const char* Bb = (const char*)BT + (size_t)n0 * ldbb + (size_t)(lane >> 3) * ldbb + swz;
  for (int k0 = kbeg; k0 < kbeg + klen; k0 += 64) {
    for (int i = wid; i < BM / 8; i += 4)
      gll16(Ab + (size_t)(i * 8) * ldab + (size_t)k0 * 2, (char*)sA + i * 1024);
    for (int i = wid; i < BN / 8; i += 4)
      gll16(Bb + (size_t)(i * 8) * ldbb + (size_t)k0 * 2, (char*)sB + i * 1024);
    __syncthreads();
#pragma unroll
    for (int kk = 0; kk < 2; kk++) {
      f16x8 af[FM], bf[FN];
#pragma unroll
      for (int i = 0; i < FM; i++) {
        int row = wm * (BM / 2) + i * 16 + l15;
        af[i] = *(const f16x8*)(sA + row * 64 + (((kk * 4 + l4) ^ (l15 & 7)) * 8));
      }
#pragma unroll
      for (int j = 0; j < FN; j++) {
        int row = wn * (BN / 2) + j * 16 + l15;
        bf[j] = *(const f16x8*)(sB + row * 64 + (((kk * 4 + l4) ^ (l15 & 7)) * 8));
      }
#pragma unroll
      for (int i = 0; i < FM; i++)
#pragma unroll
        for (int j = 0; j < FN; j++)
          acc[i][j] = __builtin_amdgcn_mfma_f32_16x16x32_f16(af[i], bf[j], acc[i][j], 0, 0, 0);
    }
    __syncthreads();
  }
  // ---- epilogues ----
  if (EPI == 0) {
#pragma unroll
    for (int i = 0; i < FM; i++) {
      int row0 = m0 + wm * (BM / 2) + i * 16 + l4 * 4;
#pragma unroll
      for (int j = 0; j < FN; j++) {
        int col = n0 + wn * (BN / 2) + j * 16 + l15;
#pragma unroll
        for (int r = 0; r < 4; r++) O1[(size_t)(row0 + r) * ldc + col] = acc[i][j][r];
      }
    }
  } else if (EPI == 1) {
    const int cb = (n0 >> 6) + wn;  // 0..23
    const int typ = cb >> 3, h = cb & 7;
    const float* bb = (typ == 0) ? c0 : (typ == 1) ? c1 : c2;
    float bias_j[FN];
#pragma unroll
    for (int j = 0; j < FN; j++) bias_j[j] = bb[h * 64 + j * 16 + l15];
    const float qs = (typ == 0) ? 0.25f : 1.0f;
#pragma unroll
    for (int i = 0; i < FM; i++) {
#pragma unroll
      for (int r = 0; r < 4; r++) {
        float y[FN];
        float ss = 0.f;
#pragma unroll
        for (int j = 0; j < FN; j++) {
          y[j] = acc[i][j][r] + bias_j[j];
          ss += y[j] * y[j];
        }
        ss += __shfl_xor(ss, 1); ss += __shfl_xor(ss, 2);
        ss += __shfl_xor(ss, 4); ss += __shfl_xor(ss, 8);
        float t = sqrtf(ss + 1.f);
        int row = m0 + wm * 64 + i * 16 + l4 * 4 + r;
        int b = row >> 10, s = row & 1023, bh = b * 8 + h;
        if (typ < 2) {
          f16* dst = (typ == 0) ? H1 : H2;
          size_t base = ((size_t)bh * 1024 + s) * 88;
#pragma unroll
          for (int j = 0; j < FN; j++) dst[base + j * 16 + l15] = (f16)(qs * y[j]);
          if (l15 == 0) dst[base + 64] = (f16)(qs * t);
        } else {
#pragma unroll
          for (int j = 0; j < FN; j++)
            H3[((size_t)bh * 80 + j * 16 + l15) * 1024 + s] = (f16)y[j];
          if (l15 == 0) H3[((size_t)bh * 80 + 64) * 1024 + s] = (f16)t;
        }
      }
    }
  } else if (EPI == 2) {
#pragma unroll
    for (int i = 0; i < FM; i++) {
#pragma unroll
      for (int r = 0; r < 4; r++) {
        int row = m0 + wm * 64 + i * 16 + l4 * 4 + r;
        float ss = 0.f;
#pragma unroll
        for (int j = 0; j < FN; j++) {
          int col = n0 + wn * 64 + j * 16 + l15;
          float gg = 0.f;
          if (col < 2047) {
            float yv = acc[i][j][r] + c0[col];
            float cc = yv * yv * yv;
            gg = 0.5f * yv * (1.f + tanhf(0.7978845608f * (yv + 0.044715f * cc)));
          }
          ss += gg * gg;
          H1[(size_t)row * 2048 + col] = (f16)gg;
        }
        ss += __shfl_xor(ss, 1); ss += __shfl_xor(ss, 2);
        ss += __shfl_xor(ss, 4); ss += __shfl_xor(ss, 8);
        if (l15 == 0) atomicAdd(ssq + row, ss);
      }
    }
  } else {  // EPI == 3
    float* O = blockIdx.z ? O2 : O1;
#pragma unroll
    for (int i = 0; i < FM; i++) {
#pragma unroll
      for (int r = 0; r < 4; r++) {
        int row = m0 + wm * (BM / 2) + i * 16 + l4 * 4 + r;
        float t = 0.f;
        if (blockIdx.z == 0) t = sqrtf(ssq[row] + 1.f);
#pragma unroll
        for (int j = 0; j < FN; j++) {
          int col = n0 + wn * (BN / 2) + j * 16 + l15;
          float v = acc[i][j][r];
          if (blockIdx.z == 0) v += t * ((col < 511) ? c0[col] : 0.f);
          O[(size_t)row * ldc + col] = v;
        }
      }
    }
  }
}

// ---------------- embed + add_time + LN1 ----------------
__global__ void k_embed(const int* __restrict__ tok, const float* __restrict__ tbl,
                        const float* __restrict__ g, const float* __restrict__ bsh,
                        float* __restrict__ x, f16* __restrict__ act) {
  __shared__ float red[4];
  const int m = blockIdx.x, tid = threadIdx.x;
  const float* e = tbl + (size_t)tok[m] * 511;
  float e0 = (tid < 511) ? e[tid] : 0.f;
  float e1 = (tid + 256 < 511) ? e[tid + 256] : 0.f;
  float s1 = block_sum(e0 + e1, red);
  float s2 = block_sum(e0 * e0 + e1 * e1, red);
  float t = sqrtf(s2 + 1.f);
  float* xr = x + (size_t)m * 512;
  if (tid == 0) xr[0] = t;
  if (tid < 511) xr[1 + tid] = e0;
  if (tid + 256 < 511) xr[257 + tid] = e1;
  float mu = s1 / 511.f;
  float var = s2 / 511.f - mu * mu;
  float inv = rsqrtf(var + 1e-5f);
  float n0 = (tid < 511) ? (e0 - mu) * inv * g[tid] + bsh[tid] : 0.f;
  float n1 = (tid + 256 < 511) ? (e1 - mu) * inv * g[tid + 256] + bsh[tid + 256] : 0.f;
  float sn = block_sum(n0 * n0 + n1 * n1, red);
  float t2 = sqrtf(sn + 1.f);
  f16* ar = act + (size_t)m * 512;
  if (tid == 0) ar[0] = (f16)t2;
  if (tid < 511) ar[1 + tid] = (f16)n0;
  if (tid + 256 < 511) ar[257 + tid] = (f16)n1;
}

// ---------------- per-wave flash attention + l_project, no LDS K/V, no barriers ----------------
__launch_bounds__(64)
__global__ void k_attn(const f16* __restrict__ qhat, const f16* __restrict__ khat,
                       const f16* __restrict__ vT, f16* __restrict__ ao) {
  __shared__ f16 sP[16 * 88];
  const int bid = blockIdx.x, bh = bid & 15, rt = 63 - (bid >> 4);
  const int lane = threadIdx.x, l15 = lane & 15, l4 = lane >> 4;
  const f16* qp = qhat + ((size_t)bh * 1024 + rt * 16) * 88;
  const f16* kp = khat + (size_t)bh * 1024 * 88;
  const f16* vp = vT + (size_t)bh * 80 * 1024;
  f16x8 qf0 = *(const f16x8*)(qp + l15 * 88 + l4 * 8);
  f16x8 qf1 = *(const f16x8*)(qp + l15 * 88 + 32 + l4 * 8);
  float qth[4];
#pragma unroll
  for (int r = 0; r < 4; r++) qth[r] = (float)qp[(l4 * 4 + r) * 88 + 64];
  f32x4 acc[5];
#pragma unroll
  for (int i = 0; i < 5; i++) acc[i] = (f32x4){0, 0, 0, 0};
  float mrun[4] = {-3e38f, -3e38f, -3e38f, -3e38f}, lrun[4] = {0, 0, 0, 0};
  const int nt = (rt >> 2) + 1;
  for (int jt = 0; jt < nt; ++jt) {
    const int j0 = jt * 64;
    const bool dt = (jt == nt - 1);
    f32x4 sc[4];
#pragma unroll
    for (int fn = 0; fn < 4; fn++) {
      const f16* kb = kp + (size_t)(j0 + fn * 16 + l15) * 88;
      f16x8 k0v = *(const f16x8*)(kb + l4 * 8);
      f16x8 k1v = *(const f16x8*)(kb + 32 + l4 * 8);
      f32x4 a = (f32x4){0, 0, 0, 0};
      a = __builtin_amdgcn_mfma_f32_16x16x32_f16(qf0, k0v, a, 0, 0, 0);
      a = __builtin_amdgcn_mfma_f32_16x16x32_f16(qf1, k1v, a, 0, 0, 0);
      sc[fn] = a;
    }
    float s[4][4];
#pragma unroll
    for (int fn = 0; fn < 4; fn++) {
      float ktc = (float)kp[(size_t)(j0 + fn * 16 + l15) * 88 + 64];
      int col = j0 + fn * 16 + l15;
#pragma unroll
      for (int r = 0; r < 4; r++) {
        int row = rt * 16 + l4 * 4 + r;
        float v = sc[fn][r] - qth[r] * ktc;
        s[fn][r] = (!dt || col <= row) ? v : -3e38f;
      }
    }
    float mnew[4], al[4], rs[4];
#pragma unroll
    for (int r = 0; r < 4; r++) {
      float t = fmaxf(fmaxf(s[0][r], s[1][r]), fmaxf(s[2][r], s[3][r]));
#pragma unroll
      for (int o = 8; o; o >>= 1) t = fmaxf(t, __shfl_xor(t, o));
      mnew[r] = fmaxf(mrun[r], t);
      al[r] = exp2f((mrun[r] - mnew[r]) * 1.44269504f);
      mrun[r] = mnew[r];
      rs[r] = 0.f;
    }
#pragma unroll
    for (int fn = 0; fn < 4; fn++)
#pragma unroll
      for (int r = 0; r < 4; r++) {
        float p = exp2f((s[fn][r] - mnew[r]) * 1.44269504f);
        rs[r] += p;
        sP[(l4 * 4 + r) * 88 + fn * 16 + l15] = (f16)p;
      }
#pragma unroll
    for (int r = 0; r < 4; r++) {
#pragma unroll
      for (int o = 8; o; o >>= 1) rs[r] += __shfl_xor(rs[r], o);
      lrun[r] = lrun[r] * al[r] + rs[r];
    }
#pragma unroll
    for (int fd = 0; fd < 5; fd++)
#pragma unroll
      for (int r = 0; r < 4; r++) acc[fd][r] *= al[r];
    __syncthreads();
#pragma unroll
    for (int ks = 0; ks < 2; ks++) {
      f16x8 pf = *(const f16x8*)(sP + l15 * 88 + ks * 32 + l4 * 8);
#pragma unroll
      for (int fd = 0; fd < 5; fd++) {
        f16x8 vf = *(const f16x8*)(vp + (size_t)(fd * 16 + l15) * 1024 + j0 + ks * 32 + l4 * 8);
        acc[fd] = __builtin_amdgcn_mfma_f32_16x16x32_f16(pf, vf, acc[fd], 0, 0, 0);
      }
    }
    __syncthreads();
  }
  const int b = bh >> 3, h = bh & 7;
#pragma unroll
  for (int r = 0; r < 4; r++) {
    float invl = 1.0f / lrun[r];
    float ss = 0.f;
    float ov[4];
#pragma unroll
    for (int fd = 0; fd < 4; fd++) {
      ov[fd] = acc[fd][r] * invl;
      ss += ov[fd] * ov[fd];
    }
#pragma unroll
    for (int o = 8; o; o >>= 1) ss += __shfl_xor(ss, o);
    float tv = acc[4][r] * invl;
    tv = __shfl(tv, lane & 48);
    float scp = rsqrtf(fmaxf(tv * tv - ss, 1e-6f));
    int row = rt * 16 + l4 * 4 + r;
    size_t rowbase = ((size_t)b * 1024 + row) * 576;
    size_t rb = rowbase + h * 65;
    if (l15 == 0) ao[rb] = (f16)(tv * scp);
#pragma unroll
    for (int fd = 0; fd < 4; fd++) ao[rb + 1 + fd * 16 + l15] = (f16)(ov[fd] * scp);
    for (int c = l15; c < 56; c += 16) ao[rowbase + 520 + c] = (f16)0.f;
  }
}

// ---------------- residual + l_project (+ optional LN), zeros ssq ----------------
__global__ void k_resproj(float* __restrict__ x, const float* __restrict__ r1,
                          const float* __restrict__ r2, int useR2,
                          const float* __restrict__ bias, const float* __restrict__ resw, int li,
                          const float* __restrict__ g, const float* __restrict__ bsh,
                          f16* __restrict__ act, int applyLN, float* __restrict__ ssq) {
  __shared__ float red[4];
  const int m = blockIdx.x, tid = threadIdx.x;
  const float* ra = r1 + (size_t)m * 512;
  const float* rb = r2 + (size_t)m * 512;
  float* xr = x + (size_t)m * 512;
  const float rw = resw[li];
  if (tid == 0) ssq[m] = 0.f;
  float y0 = 0.f, y1 = 0.f;
  if (tid < 511) { y0 = ra[tid] + bias[tid]; if (useR2) y0 += rb[tid]; }
  if (tid + 256 < 511) { y1 = ra[tid + 256] + bias[tid + 256]; if (useR2) y1 += rb[tid + 256]; }
  float s2 = block_sum(y0 * y0 + y1 * y1, red);
  float tax = sqrtf(s2 + 1.f);
  float xt = xr[0];
  float u0 = (tid < 511) ? xr[1 + tid] + rw * y0 : 0.f;
  float u1 = (tid + 256 < 511) ? xr[257 + tid] + rw * y1 : 0.f;
  float ut = xt + rw * tax;
  float su = block_sum(u0 + u1, red);
  float su2 = block_sum(u0 * u0 + u1 * u1, red);
  float scp = rsqrtf(fmaxf(ut * ut - su2, 1e-6f));
  float nx0 = u0 * scp, nx1 = u1 * scp, nxt = ut * scp;
  if (tid == 0) xr[0] = nxt;
  if (tid < 511) xr[1 + tid] = nx0;
  if (tid + 256 < 511) xr[257 + tid] = nx1;
  f16* ar = act + (size_t)m * 512;
  if (applyLN) {
    float mu = su * scp / 511.f;
    float var = su2 * scp * scp / 511.f - mu * mu;
    float inv = rsqrtf(var + 1e-5f);
    float n0 = (tid < 511) ? (nx0 - mu) * inv * g[tid] + bsh[tid] : 0.f;
    float n1 = (tid + 256 < 511) ? (nx1 - mu) * inv * g[tid + 256] + bsh[tid + 256] : 0.f;
    float sn = block_sum(n0 * n0 + n1 * n1, red);
    float t2 = sqrtf(sn + 1.f);
    if (tid == 0) ar[0] = (f16)t2;
    if (tid < 511) ar[1 + tid] = (f16)n0;
    if (tid + 256 < 511) ar[257 + tid] = (f16)n1;
  } else {
    if (tid == 0) ar[0] = (f16)nxt;
    if (tid < 511) ar[1 + tid] = (f16)nx0;
    if (tid + 256 < 511) ar[257 + tid] = (f16)nx1;
  }
}

// ---------------- final bias + LN -> out ----------------
__global__ void k_final(const float* __restrict__ raw, const float* __restrict__ bias,
                        const float* __restrict__ g, const float* __restrict__ bsh,
                        float* __restrict__ out) {
  __shared__ float red[4];
  const int m = blockIdx.x, tid = threadIdx.x;
  const float* rr = raw + (size_t)m * 512;
  float y0 = (tid < 511) ? rr[tid] + bias[tid] : 0.f;
  float y1 = (tid + 256 < 511) ? rr[tid + 256] + bias[tid + 256] : 0.f;
  float s1 = block_sum(y0 + y1, red);
  float s2 = block_sum(y0 * y0 + y1 * y1, red);
  float mu = s1 / 511.f;
  float var = s2 / 511.f - mu * mu;
  float inv = rsqrtf(var + 1e-5f);
  float n0 = (tid < 511) ? (y0 - mu) * inv * g[tid] + bsh[tid] : 0.f;
  float n1 = (tid + 256 < 511) ? (y1 - mu) * inv * g[tid + 256] + bsh[tid + 256] : 0.f;
  float sn = block_sum(n0 * n0 + n1 * n1, red);
  float t2 = sqrtf(sn + 1.f);
  float* orow = out + (size_t)m * 512;
  if (tid == 0) orow[0] = t2;
  if (tid < 511) orow[1 + tid] = n0;
  if (tid + 256 < 511) orow[257 + tid] = n1;
}

extern "C" void kernel_launch(void* const* d_in, const int* in_sizes, int n_in,
                              void* d_out, int out_size, void* d_ws, size_t ws_size,
                              hipStream_t stream) {
  (void)in_sizes; (void)n_in; (void)out_size; (void)ws_size;
  const int* tok = (const int*)d_in[0];
  const float* etab = (const float*)d_in[1];
  const float* Wq = (const float*)d_in[2];
  const float* bq = (const float*)d_in[3];
  const float* Wk = (const float*)d_in[4];
  const float* bk = (const float*)d_in[5];
  const float* Wv = (const float*)d_in[6];
  const float* bv = (const float*)d_in[7];
  const float* Wo = (const float*)d_in[8];
  const float* bo = (const float*)d_in[9];
  const float* ln1g = (const float*)d_in[10];
  const float* ln1b = (const float*)d_in[11];
  const float* ln2g = (const float*)d_in[12];
  const float* ln2b = (const float*)d_in[13];
  const float* Wfc = (const float*)d_in[14];
  const float* bfc = (const float*)d_in[15];
  const float* Wpr = (const float*)d_in[16];
  const float* bpr = (const float*)d_in[17];
  const float* rw1 = (const float*)d_in[18];
  const float* rw2 = (const float*)d_in[19];
  const float* Wfin = (const float*)d_in[20];
  const float* bfin = (const float*)d_in[21];
  const float* lnfg = (const float*)d_in[22];
  const float* lnfb = (const float*)d_in[23];

  char* wsb = (char*)d_ws;
  size_t off = 0;
  auto alloc = [&](size_t bytes) -> char* {
    char* p = wsb + off;
    off = (off + bytes + 1023) & ~(size_t)1023;
    return p;
  };
  float* x = (float*)alloc(2048ull * 512 * 4);
  f16* actA = (f16*)alloc(2048ull * 512 * 2);
  float* raw1 = (float*)alloc(2048ull * 512 * 4);
  float* raw2 = (float*)alloc(2048ull * 512 * 4);
  float* ssq = (float*)alloc(2048ull * 4);
  f16* qhat = (f16*)alloc(16ull * 1024 * 88 * 2);
  f16* khat = (f16*)alloc(16ull * 1024 * 88 * 2);
  f16* vT = (f16*)alloc(16ull * 80 * 1024 * 2);
  f16* ao = (f16*)alloc(2048ull * 576 * 2);
  f16* fcact = (f16*)alloc(2048ull * 2048 * 2);
  f16* wqkvT = (f16*)alloc(12ull * 1536 * 512 * 2);
  f16* woT = (f16*)alloc(12ull * 512 * 576 * 2);
  f16* wfcT = (f16*)alloc(12ull * 2048 * 512 * 2);
  f16* wprT = (f16*)alloc(12ull * 512 * 2048 * 2);
  f16* wfinT = (f16*)alloc(512ull * 512 * 2);

  // ---- all weight transposes hoisted (per-layer via blockIdx.z) ----
  k_trans3<<<dim3(16, 16, 36), dim3(32, 8), 0, stream>>>(Wq, Wk, Wv, wqkvT);
  k_trans<<<dim3(16, 18, 12), dim3(32, 8), 0, stream>>>(Wo, woT, 520, 511, 576,
                                                        520ull * 511, 512ull * 576);
  k_trans<<<dim3(64, 16, 12), dim3(32, 8), 0, stream>>>(Wfc, wfcT, 512, 2047, 512,
                                                        512ull * 2047, 2048ull * 512);
  k_trans<<<dim3(16, 64, 12), dim3(32, 8), 0, stream>>>(Wpr + 511, wprT, 2047, 511, 2048,
                                                        2048ull * 511, 512ull * 2048);
  k_trans<<<dim3(16, 16, 1), dim3(32, 8), 0, stream>>>(Wfin, wfinT, 512, 511, 512, 0, 0);

  k_embed<<<2048, 256, 0, stream>>>(tok, etab, ln1g, ln1b, x, actA);

  for (int li = 0; li < 12; li++) {
    const f16* wqkvT_l = wqkvT + (size_t)li * 1536 * 512;
    const f16* woT_l = woT + (size_t)li * 512 * 576;
    const f16* wfcT_l = wfcT + (size_t)li * 2048 * 512;
    const f16* wprT_l = wprT + (size_t)li * 512 * 2048;
    const float* Wpr_l = Wpr + (size_t)li * 2048 * 511;
    const float* bq_l = bq + (size_t)li * 512;
    const float* bk_l = bk + (size_t)li * 512;
    const float* bv_l = bv + (size_t)li * 512;
    const float* bo_l = bo + (size_t)li * 511;
    const float* bfc_l = bfc + (size_t)li * 2047;
    const float* bpr_l = bpr + (size_t)li * 511;
    const float* ln2g_l = ln2g + (size_t)li * 511;
    const float* ln2b_l = ln2b + (size_t)li * 511;

    k_gemm<128, 128, 1><<<dim3(16, 12, 1), 256, 0, stream>>>(
        actA, wqkvT_l, 512, 512, 512, nullptr, nullptr, 0,
        bq_l, bk_l, bv_l, nullptr, qhat, khat, vT);
    k_attn<<<1024, 64, 0, stream>>>(qhat, khat, vT, ao);
    k_gemm<64, 64, 0><<<dim3(32, 8, 1), 256, 0, stream>>>(
        ao, woT_l, 576, 576, 576, raw1, nullptr, 512,
        nullptr, nullptr, nullptr, nullptr, nullptr, nullptr, nullptr);
    k_resproj<<<2048, 256, 0, stream>>>(x, raw1, raw1, 0, bo_l, rw1, li,
                                        ln2g_l, ln2b_l, actA, 1, ssq);
    k_gemm<128, 128, 2><<<dim3(16, 16, 1), 256, 0, stream>>>(
        actA, wfcT_l, 512, 512, 512, nullptr, nullptr, 0,
        bfc_l, nullptr, nullptr, ssq, fcact, nullptr, nullptr);
    k_gemm<64, 64, 3><<<dim3(32, 8, 2), 256, 0, stream>>>(
        fcact, wprT_l, 2048, 2048, 1024, raw1, raw2, 512,
        Wpr_l, nullptr, nullptr, ssq, nullptr, nullptr, nullptr);
    const float* ng = (li < 11) ? ln1g + (size_t)(li + 1) * 511 : ln1g;
    const float* nb = (li < 11) ? ln1b + (size_t)(li + 1) * 511 : ln1b;
    k_resproj<<<2048, 256, 0, stream>>>(x, raw1, raw2, 1, bpr_l, rw2, li,
                                        ng, nb, actA, (li < 11) ? 1 : 0, ssq);
  }

  k_gemm<64, 64, 0><<<dim3(32, 8, 1), 256, 0, stream>>>(
      actA, wfinT, 512, 512, 512, raw1, nullptr, 512,
      nullptr, nullptr, nullptr, nullptr, nullptr, nullptr, nullptr);
  k_final<<<2048, 256, 0, stream>>>(raw1, bfin, lnfg, lnfb, (float*)d_out);
}